// Round 4
// baseline (270.396 us; speedup 1.0000x reference)
//
#include <hip/hip_runtime.h>
#include <hip/hip_bf16.h>

#define N_NODES 100000
#define N_EDGES 1600000
#define FEAT 128
#define SLOTS 64
#define NBINS 2000
#define BIN_NODES 50   // N_NODES / NBINS exactly
#define PAD 16         // ints per padded counter slot (one 64B line)

typedef __bf16 bf16x8 __attribute__((ext_vector_type(8)));
typedef unsigned short ushort8 __attribute__((ext_vector_type(8)));
typedef float f32x4 __attribute__((ext_vector_type(4)));

__device__ __forceinline__ unsigned short f2bf_bits(float f) {
    unsigned u = __builtin_bit_cast(unsigned, f);
    unsigned r = (u + 0x7fffu + ((u >> 16) & 1u)) >> 16;
    return (unsigned short)r;
}
__device__ __forceinline__ float bf2f(unsigned short b) {
    return __builtin_bit_cast(float, (unsigned)b << 16);
}

// ---------------------------------------------------------------------------
// 1) x (fp32) -> xbf (bf16 bits)
// ---------------------------------------------------------------------------
__global__ void prep_kernel(const float* __restrict__ x, unsigned short* __restrict__ xbf) {
    int t = blockIdx.x * blockDim.x + threadIdx.x;
    if (t >= N_NODES * FEAT / 8) return;
    float4 a = ((const float4*)x)[t * 2];
    float4 b = ((const float4*)x)[t * 2 + 1];
    ushort8 u;
    u[0] = f2bf_bits(a.x); u[1] = f2bf_bits(a.y);
    u[2] = f2bf_bits(a.z); u[3] = f2bf_bits(a.w);
    u[4] = f2bf_bits(b.x); u[5] = f2bf_bits(b.y);
    u[6] = f2bf_bits(b.z); u[7] = f2bf_bits(b.w);
    ((ushort8*)xbf)[t] = u;
}

// ---------------------------------------------------------------------------
// 2) per-bin edge histogram (padded counters: one line per bin)
// ---------------------------------------------------------------------------
__global__ void hist_kernel(const int* __restrict__ ei, int* __restrict__ hist) {
    int e = blockIdx.x * blockDim.x + threadIdx.x;
    if (e >= N_EDGES) return;
    int dst = ei[N_EDGES + e];
    atomicAdd(&hist[(dst / BIN_NODES) * PAD], 1);
}

// ---------------------------------------------------------------------------
// 3) exclusive scan of 2000 bins (single block, 1024 threads, 2 bins each)
//    -> binptr[0..NBINS], padded cursors pcur
// ---------------------------------------------------------------------------
__global__ __launch_bounds__(1024) void scan_kernel(const int* __restrict__ hist,
                                                    int* __restrict__ binptr,
                                                    int* __restrict__ pcur) {
    __shared__ int wpart[16];
    const int t = threadIdx.x;
    const int b0 = t * 2;
    int h0 = 0, h1 = 0;
    if (b0 < NBINS)     h0 = hist[b0 * PAD];
    if (b0 + 1 < NBINS) h1 = hist[(b0 + 1) * PAD];
    const int s = h0 + h1;
    const int lane = t & 63, wid = t >> 6;
    int incl = s;
    #pragma unroll
    for (int d = 1; d < 64; d <<= 1) {
        int up = __shfl_up(incl, d);
        if (lane >= d) incl += up;
    }
    if (lane == 63) wpart[wid] = incl;
    __syncthreads();
    if (t == 0) {
        int run = 0;
        #pragma unroll
        for (int i = 0; i < 16; ++i) { int v = wpart[i]; wpart[i] = run; run += v; }
    }
    __syncthreads();
    const int excl = wpart[wid] + incl - s;
    if (b0 < NBINS) {
        binptr[b0] = excl;
        pcur[b0 * PAD] = excl;
    }
    if (b0 + 1 < NBINS) {
        binptr[b0 + 1] = excl + h0;
        pcur[(b0 + 1) * PAD] = excl + h0;
    }
    if (t == 0) binptr[NBINS] = N_EDGES;
}

// ---------------------------------------------------------------------------
// 4) scatter edges into bin-sorted array; payload packed: src | (local_dst<<20)
//    writes are cursor-sequential per bin -> lines fill before eviction
// ---------------------------------------------------------------------------
__global__ void scatter_kernel(const int* __restrict__ ei,
                               int* __restrict__ pcur, int* __restrict__ ebin) {
    int e = blockIdx.x * blockDim.x + threadIdx.x;
    if (e >= N_EDGES) return;
    int dst = ei[N_EDGES + e];
    int src = ei[e];
    int b = dst / BIN_NODES;
    int ln = dst - b * BIN_NODES;
    int pos = atomicAdd(&pcur[b * PAD], 1);
    ebin[pos] = src | (ln << 20);
}

// ---------------------------------------------------------------------------
// 5) per-bin aggregation: LDS bucket build + atomic-free gather-mean.
//    One block per bin (50 nodes); wave per node, 4 rows in flight.
// ---------------------------------------------------------------------------
__global__ __launch_bounds__(256) void agg_kernel(
    const unsigned short* __restrict__ xbf, const int* __restrict__ binptr,
    const int* __restrict__ ebin, unsigned short* __restrict__ xbarbf,
    int* __restrict__ degs) {
    __shared__ int lcnt[BIN_NODES];
    __shared__ int lbuck[BIN_NODES][SLOTS];
    const int b = blockIdx.x;
    const int tid = threadIdx.x;
    if (tid < BIN_NODES) lcnt[tid] = 0;
    __syncthreads();
    const int start = binptr[b], end = binptr[b + 1];
    for (int i = start + tid; i < end; i += 256) {
        int v = ebin[i];
        int src = v & 0xFFFFF;
        int ln = v >> 20;
        int pos = atomicAdd(&lcnt[ln], 1);
        if (pos < SLOTS) lbuck[ln][pos] = src;
    }
    __syncthreads();
    const int wave = tid >> 6, lane = tid & 63;
    const int g = lane >> 4, c = (lane & 15) * 8;
    for (int ln = wave; ln < BIN_NODES; ln += 4) {
        int deg = lcnt[ln];
        int k = deg > SLOTS ? SLOTS : deg;
        float acc[8];
        #pragma unroll
        for (int i = 0; i < 8; ++i) acc[i] = 0.f;
        for (int base = 0; base < k; base += 4) {
            int j = base + g;
            if (j < k) {
                int src = lbuck[ln][j];
                ushort8 v = *(const ushort8*)(xbf + (size_t)src * FEAT + c);
                #pragma unroll
                for (int i = 0; i < 8; ++i) acc[i] += bf2f(v[i]);
            }
        }
        #pragma unroll
        for (int i = 0; i < 8; ++i) {
            acc[i] += __shfl_xor(acc[i], 16);
            acc[i] += __shfl_xor(acc[i], 32);
        }
        int n = b * BIN_NODES + ln;
        if (lane < 16) {
            float inv = 1.0f / (float)(deg > 0 ? deg : 1);
            ushort8 o;
            #pragma unroll
            for (int i = 0; i < 8; ++i) o[i] = f2bf_bits(acc[i] * inv);
            *(ushort8*)(xbarbf + (size_t)n * FEAT + c) = o;
        }
        if (lane == 0) degs[n] = deg;
    }
}

// ---------------------------------------------------------------------------
// 6) fused GEMM: out = xbar @ Wl^T + bl*[deg>0] + x @ Wr^T  (A already bf16)
// ---------------------------------------------------------------------------
__global__ __launch_bounds__(256) void gemm_kernel(
    const unsigned short* __restrict__ xbf, const unsigned short* __restrict__ xbarbf,
    const float* __restrict__ Wl, const float* __restrict__ bl,
    const float* __restrict__ Wr, const int* __restrict__ degs,
    float* __restrict__ out) {

    __shared__ unsigned short lM[32][136];
    __shared__ unsigned short lX[32][136];

    const int tid = threadIdx.x;
    const int wave = tid >> 6, lane = tid & 63;
    const int l15 = lane & 15, lhi = lane >> 4;
    const int colbase = wave * 32;

    bf16x8 bB[2][8];
    float biasv[2];
    #pragma unroll
    for (int ct = 0; ct < 2; ++ct) {
        int col = colbase + ct * 16 + l15;
        biasv[ct] = bl[col];
        const float* wl = Wl + (size_t)col * 128;
        const float* wr = Wr + (size_t)col * 128;
        #pragma unroll
        for (int s = 0; s < 4; ++s) {
            int kb = lhi * 8 + s * 32;
            bf16x8 b, cfr;
            #pragma unroll
            for (int i = 0; i < 8; ++i) {
                b[i]   = __builtin_bit_cast(__bf16, f2bf_bits(wl[kb + i]));
                cfr[i] = __builtin_bit_cast(__bf16, f2bf_bits(wr[kb + i]));
            }
            bB[ct][s] = b;
            bB[ct][4 + s] = cfr;
        }
    }

    const int ntiles = N_NODES / 32;
    for (int tile = blockIdx.x; tile < ntiles; tile += gridDim.x) {
        const int row0 = tile * 32;
        {
            int r = tid >> 3;
            int c0 = (tid & 7) * 16;
            const unsigned short* sm = xbarbf + (size_t)(row0 + r) * FEAT + c0;
            const unsigned short* sx = xbf + (size_t)(row0 + r) * FEAT + c0;
            *(ushort8*)&lM[r][c0]     = *(const ushort8*)(sm);
            *(ushort8*)&lM[r][c0 + 8] = *(const ushort8*)(sm + 8);
            *(ushort8*)&lX[r][c0]     = *(const ushort8*)(sx);
            *(ushort8*)&lX[r][c0 + 8] = *(const ushort8*)(sx + 8);
        }
        __syncthreads();

        f32x4 acc[2][2];
        #pragma unroll
        for (int rh = 0; rh < 2; ++rh)
            #pragma unroll
            for (int ct = 0; ct < 2; ++ct) acc[rh][ct] = (f32x4){0.f, 0.f, 0.f, 0.f};

        #pragma unroll
        for (int rh = 0; rh < 2; ++rh) {
            int arow = rh * 16 + l15;
            bf16x8 aM[4], aX[4];
            #pragma unroll
            for (int s = 0; s < 4; ++s) {
                aM[s] = __builtin_bit_cast(bf16x8, *(const ushort8*)&lM[arow][lhi * 8 + s * 32]);
                aX[s] = __builtin_bit_cast(bf16x8, *(const ushort8*)&lX[arow][lhi * 8 + s * 32]);
            }
            #pragma unroll
            for (int ct = 0; ct < 2; ++ct) {
                f32x4 a = acc[rh][ct];
                #pragma unroll
                for (int s = 0; s < 4; ++s)
                    a = __builtin_amdgcn_mfma_f32_16x16x32_bf16(aM[s], bB[ct][s], a, 0, 0, 0);
                #pragma unroll
                for (int s = 0; s < 4; ++s)
                    a = __builtin_amdgcn_mfma_f32_16x16x32_bf16(aX[s], bB[ct][4 + s], a, 0, 0, 0);
                acc[rh][ct] = a;
            }
        }

        #pragma unroll
        for (int rh = 0; rh < 2; ++rh)
            #pragma unroll
            for (int ct = 0; ct < 2; ++ct) {
                int col = colbase + ct * 16 + l15;
                #pragma unroll
                for (int j = 0; j < 4; ++j) {
                    int r = row0 + rh * 16 + lhi * 4 + j;
                    float bias = (degs[r] > 0) ? biasv[ct] : 0.f;
                    out[(size_t)r * FEAT + col] = acc[rh][ct][j] + bias;
                }
            }
        __syncthreads();
    }
}

extern "C" void kernel_launch(void* const* d_in, const int* in_sizes, int n_in,
                              void* d_out, int out_size, void* d_ws, size_t ws_size,
                              hipStream_t stream) {
    const float* x  = (const float*)d_in[0];
    const int*   ei = (const int*)d_in[1];
    const float* Wl = (const float*)d_in[2];
    const float* bl = (const float*)d_in[3];
    const float* Wr = (const float*)d_in[4];
    float* out = (float*)d_out;

    unsigned short* xbf    = (unsigned short*)d_ws;                  // 25.6 MB
    unsigned short* xbarbf = xbf + (size_t)N_NODES * FEAT;           // 25.6 MB
    int* degs   = (int*)(xbarbf + (size_t)N_NODES * FEAT);           // 400 KB
    int* hist   = degs + N_NODES;                                    // 128 KB (padded)
    int* pcur   = hist + NBINS * PAD;                                // 128 KB (padded)
    int* binptr = pcur + NBINS * PAD;                                // ~8 KB
    int* ebin   = binptr + NBINS + 1 + 63;                           // 6.4 MB

    hipMemsetAsync(hist, 0, (size_t)NBINS * PAD * sizeof(int), stream);

    prep_kernel<<<(N_NODES * FEAT / 8 + 255) / 256, 256, 0, stream>>>(x, xbf);
    hist_kernel<<<(N_EDGES + 255) / 256, 256, 0, stream>>>(ei, hist);
    scan_kernel<<<1, 1024, 0, stream>>>(hist, binptr, pcur);
    scatter_kernel<<<(N_EDGES + 255) / 256, 256, 0, stream>>>(ei, pcur, ebin);
    agg_kernel<<<NBINS, 256, 0, stream>>>(xbf, binptr, ebin, xbarbf, degs);
    gemm_kernel<<<1024, 256, 0, stream>>>(xbf, xbarbf, Wl, bl, Wr, degs, out);
}

// Round 5
// 181.451 us; speedup vs baseline: 1.4902x; 1.4902x over previous
//
#include <hip/hip_runtime.h>
#include <hip/hip_bf16.h>

#define N_NODES 100000
#define N_EDGES 1600000
#define FEAT 128
#define NBINS 1024
#define BIN_NODES 98          // 1024*98 = 100352 >= 100000
#define PBLK 64               // partition blocks
#define CHUNK (N_EDGES / PBLK)  // 25000 (exact)
#define CSR_MAX 2048          // per-bin edges: mean 1562, sigma ~40 -> +12 sigma

typedef __bf16 bf16x8 __attribute__((ext_vector_type(8)));
typedef unsigned short ushort8 __attribute__((ext_vector_type(8)));
typedef float f32x4 __attribute__((ext_vector_type(4)));

__device__ __forceinline__ unsigned short f2bf_bits(float f) {
    unsigned u = __builtin_bit_cast(unsigned, f);
    unsigned r = (u + 0x7fffu + ((u >> 16) & 1u)) >> 16;
    return (unsigned short)r;
}
__device__ __forceinline__ float bf2f(unsigned short b) {
    return __builtin_bit_cast(float, (unsigned)b << 16);
}

// ---------------------------------------------------------------------------
// 1) x (fp32) -> xbf (bf16 bits)
// ---------------------------------------------------------------------------
__global__ void prep_kernel(const float* __restrict__ x, unsigned short* __restrict__ xbf) {
    int t = blockIdx.x * blockDim.x + threadIdx.x;
    if (t >= N_NODES * FEAT / 8) return;
    float4 a = ((const float4*)x)[t * 2];
    float4 b = ((const float4*)x)[t * 2 + 1];
    ushort8 u;
    u[0] = f2bf_bits(a.x); u[1] = f2bf_bits(a.y);
    u[2] = f2bf_bits(a.z); u[3] = f2bf_bits(a.w);
    u[4] = f2bf_bits(b.x); u[5] = f2bf_bits(b.y);
    u[6] = f2bf_bits(b.z); u[7] = f2bf_bits(b.w);
    ((ushort8*)xbf)[t] = u;
}

// ---------------------------------------------------------------------------
// 2) partition pass A: per-(block,bin) histogram. histm[bin*PBLK + blk]
// ---------------------------------------------------------------------------
__global__ __launch_bounds__(256) void partA_kernel(const int* __restrict__ ei,
                                                    int* __restrict__ histm) {
    __shared__ int h[NBINS];
    const int tid = threadIdx.x, b = blockIdx.x;
    for (int i = tid; i < NBINS; i += 256) h[i] = 0;
    __syncthreads();
    const int4* dsts = (const int4*)(ei + N_EDGES + b * CHUNK);
    for (int i = tid; i < CHUNK / 4; i += 256) {
        int4 d = dsts[i];
        atomicAdd(&h[d.x / BIN_NODES], 1);
        atomicAdd(&h[d.y / BIN_NODES], 1);
        atomicAdd(&h[d.z / BIN_NODES], 1);
        atomicAdd(&h[d.w / BIN_NODES], 1);
    }
    __syncthreads();
    for (int i = tid; i < NBINS; i += 256) histm[i * PBLK + b] = h[i];
}

// ---------------------------------------------------------------------------
// 3) in-place exclusive scan of histm (65536 ints; 1024 thr x 64 each)
// ---------------------------------------------------------------------------
__global__ __launch_bounds__(1024) void scan_kernel(int* __restrict__ m) {
    __shared__ int wsum[16];
    const int t = threadIdx.x, lane = t & 63, wid = t >> 6;
    const int qbase = t * 16;  // int4 index
    int s = 0;
    #pragma unroll
    for (int i = 0; i < 16; ++i) {
        int4 v = ((const int4*)m)[qbase + i];
        s += v.x + v.y + v.z + v.w;
    }
    int incl = s;
    #pragma unroll
    for (int d = 1; d < 64; d <<= 1) {
        int up = __shfl_up(incl, d);
        if (lane >= d) incl += up;
    }
    if (lane == 63) wsum[wid] = incl;
    __syncthreads();
    if (t == 0) {
        int run = 0;
        #pragma unroll
        for (int i = 0; i < 16; ++i) { int v = wsum[i]; wsum[i] = run; run += v; }
    }
    __syncthreads();
    int excl = wsum[wid] + incl - s;
    #pragma unroll
    for (int i = 0; i < 16; ++i) {
        int4 v = ((const int4*)m)[qbase + i];
        int4 w;
        w.x = excl; excl += v.x;
        w.y = excl; excl += v.y;
        w.z = excl; excl += v.z;
        w.w = excl; excl += v.w;
        ((int4*)m)[qbase + i] = w;
    }
}

// ---------------------------------------------------------------------------
// 4) partition pass B: scatter packed (src | ln<<17) into block-private,
//    cursor-sequential regions of ebin.
// ---------------------------------------------------------------------------
__global__ __launch_bounds__(256) void partB_kernel(const int* __restrict__ ei,
                                                    const int* __restrict__ offm,
                                                    int* __restrict__ ebin) {
    __shared__ int cur[NBINS];
    const int tid = threadIdx.x, b = blockIdx.x;
    for (int i = tid; i < NBINS; i += 256) cur[i] = offm[i * PBLK + b];
    __syncthreads();
    const int4* srcs = (const int4*)(ei + b * CHUNK);
    const int4* dsts = (const int4*)(ei + N_EDGES + b * CHUNK);
    for (int i = tid; i < CHUNK / 4; i += 256) {
        int4 s4 = srcs[i];
        int4 d4 = dsts[i];
        int bin, ln, pos;
        bin = d4.x / BIN_NODES; ln = d4.x - bin * BIN_NODES;
        pos = atomicAdd(&cur[bin], 1); ebin[pos] = s4.x | (ln << 17);
        bin = d4.y / BIN_NODES; ln = d4.y - bin * BIN_NODES;
        pos = atomicAdd(&cur[bin], 1); ebin[pos] = s4.y | (ln << 17);
        bin = d4.z / BIN_NODES; ln = d4.z - bin * BIN_NODES;
        pos = atomicAdd(&cur[bin], 1); ebin[pos] = s4.z | (ln << 17);
        bin = d4.w / BIN_NODES; ln = d4.w - bin * BIN_NODES;
        pos = atomicAdd(&cur[bin], 1); ebin[pos] = s4.w | (ln << 17);
    }
}

// ---------------------------------------------------------------------------
// 5) per-bin aggregation: exact LDS CSR (hist -> scan -> fill) + gather-mean.
//    One block per bin (98 nodes); wave per node, 4 rows in flight.
// ---------------------------------------------------------------------------
__global__ __launch_bounds__(256) void agg_kernel(
    const unsigned short* __restrict__ xbf, const int* __restrict__ offm,
    const int* __restrict__ ebin, unsigned short* __restrict__ xbarbf,
    int* __restrict__ degs) {
    __shared__ int lcnt[BIN_NODES];
    __shared__ int loff[BIN_NODES];
    __shared__ int lcur[BIN_NODES];
    __shared__ int lcsr[CSR_MAX];
    __shared__ int wpart[2];

    const int b = blockIdx.x, tid = threadIdx.x;
    int nb = N_NODES - b * BIN_NODES;
    if (nb <= 0) return;          // trailing empty bins
    if (nb > BIN_NODES) nb = BIN_NODES;
    const int start = offm[b * PBLK];
    const int end = (b == NBINS - 1) ? N_EDGES : offm[(b + 1) * PBLK];

    if (tid < BIN_NODES) lcnt[tid] = 0;
    __syncthreads();
    for (int i = start + tid; i < end; i += 256)
        atomicAdd(&lcnt[ebin[i] >> 17], 1);
    __syncthreads();

    // exclusive scan of 98 counters using waves 0 and 1
    const int lane = tid & 63, wave = tid >> 6;
    if (wave < 2) {
        int idx = wave * 64 + lane;
        int c = (idx < BIN_NODES) ? lcnt[idx] : 0;
        int incl = c;
        #pragma unroll
        for (int d = 1; d < 64; d <<= 1) {
            int up = __shfl_up(incl, d);
            if (lane >= d) incl += up;
        }
        if (lane == 63) wpart[wave] = incl;
        if (idx < BIN_NODES) loff[idx] = incl - c;
    }
    __syncthreads();
    if (wave == 1) {
        int idx = 64 + lane;
        if (idx < BIN_NODES) loff[idx] += wpart[0];
    }
    __syncthreads();
    if (tid < BIN_NODES) lcur[tid] = loff[tid];
    __syncthreads();

    for (int i = start + tid; i < end; i += 256) {
        int v = ebin[i];
        int ln = v >> 17;
        int pos = atomicAdd(&lcur[ln], 1);
        lcsr[pos] = v & 0x1FFFF;
    }
    __syncthreads();

    const int g = lane >> 4, c = (lane & 15) * 8;
    for (int ln = wave; ln < nb; ln += 4) {
        const int deg = lcnt[ln];
        const int s0 = loff[ln];
        float acc[8];
        #pragma unroll
        for (int i = 0; i < 8; ++i) acc[i] = 0.f;
        for (int base = 0; base < deg; base += 4) {
            int j = base + g;
            if (j < deg) {
                int src = lcsr[s0 + j];
                ushort8 v = *(const ushort8*)(xbf + (size_t)src * FEAT + c);
                #pragma unroll
                for (int i = 0; i < 8; ++i) acc[i] += bf2f(v[i]);
            }
        }
        #pragma unroll
        for (int i = 0; i < 8; ++i) {
            acc[i] += __shfl_xor(acc[i], 16);
            acc[i] += __shfl_xor(acc[i], 32);
        }
        const int n = b * BIN_NODES + ln;
        if (lane < 16) {
            float inv = 1.0f / (float)(deg > 0 ? deg : 1);
            ushort8 o;
            #pragma unroll
            for (int i = 0; i < 8; ++i) o[i] = f2bf_bits(acc[i] * inv);
            *(ushort8*)(xbarbf + (size_t)n * FEAT + c) = o;
        }
        if (lane == 0) degs[n] = deg;
    }
}

// ---------------------------------------------------------------------------
// 6) fused GEMM: out = xbar @ Wl^T + bl*[deg>0] + x @ Wr^T  (A already bf16)
// ---------------------------------------------------------------------------
__global__ __launch_bounds__(256) void gemm_kernel(
    const unsigned short* __restrict__ xbf, const unsigned short* __restrict__ xbarbf,
    const float* __restrict__ Wl, const float* __restrict__ bl,
    const float* __restrict__ Wr, const int* __restrict__ degs,
    float* __restrict__ out) {

    __shared__ unsigned short lM[32][136];
    __shared__ unsigned short lX[32][136];

    const int tid = threadIdx.x;
    const int wave = tid >> 6, lane = tid & 63;
    const int l15 = lane & 15, lhi = lane >> 4;
    const int colbase = wave * 32;

    bf16x8 bB[2][8];
    float biasv[2];
    #pragma unroll
    for (int ct = 0; ct < 2; ++ct) {
        int col = colbase + ct * 16 + l15;
        biasv[ct] = bl[col];
        const float* wl = Wl + (size_t)col * 128;
        const float* wr = Wr + (size_t)col * 128;
        #pragma unroll
        for (int s = 0; s < 4; ++s) {
            int kb = lhi * 8 + s * 32;
            bf16x8 bfr, cfr;
            #pragma unroll
            for (int i = 0; i < 8; ++i) {
                bfr[i] = __builtin_bit_cast(__bf16, f2bf_bits(wl[kb + i]));
                cfr[i] = __builtin_bit_cast(__bf16, f2bf_bits(wr[kb + i]));
            }
            bB[ct][s] = bfr;
            bB[ct][4 + s] = cfr;
        }
    }

    const int ntiles = N_NODES / 32;
    for (int tile = blockIdx.x; tile < ntiles; tile += gridDim.x) {
        const int row0 = tile * 32;
        {
            int r = tid >> 3;
            int c0 = (tid & 7) * 16;
            const unsigned short* sm = xbarbf + (size_t)(row0 + r) * FEAT + c0;
            const unsigned short* sx = xbf + (size_t)(row0 + r) * FEAT + c0;
            *(ushort8*)&lM[r][c0]     = *(const ushort8*)(sm);
            *(ushort8*)&lM[r][c0 + 8] = *(const ushort8*)(sm + 8);
            *(ushort8*)&lX[r][c0]     = *(const ushort8*)(sx);
            *(ushort8*)&lX[r][c0 + 8] = *(const ushort8*)(sx + 8);
        }
        __syncthreads();

        f32x4 acc[2][2];
        #pragma unroll
        for (int rh = 0; rh < 2; ++rh)
            #pragma unroll
            for (int ct = 0; ct < 2; ++ct) acc[rh][ct] = (f32x4){0.f, 0.f, 0.f, 0.f};

        #pragma unroll
        for (int rh = 0; rh < 2; ++rh) {
            int arow = rh * 16 + l15;
            bf16x8 aM[4], aX[4];
            #pragma unroll
            for (int s = 0; s < 4; ++s) {
                aM[s] = __builtin_bit_cast(bf16x8, *(const ushort8*)&lM[arow][lhi * 8 + s * 32]);
                aX[s] = __builtin_bit_cast(bf16x8, *(const ushort8*)&lX[arow][lhi * 8 + s * 32]);
            }
            #pragma unroll
            for (int ct = 0; ct < 2; ++ct) {
                f32x4 a = acc[rh][ct];
                #pragma unroll
                for (int s = 0; s < 4; ++s)
                    a = __builtin_amdgcn_mfma_f32_16x16x32_bf16(aM[s], bB[ct][s], a, 0, 0, 0);
                #pragma unroll
                for (int s = 0; s < 4; ++s)
                    a = __builtin_amdgcn_mfma_f32_16x16x32_bf16(aX[s], bB[ct][4 + s], a, 0, 0, 0);
                acc[rh][ct] = a;
            }
        }

        #pragma unroll
        for (int rh = 0; rh < 2; ++rh)
            #pragma unroll
            for (int ct = 0; ct < 2; ++ct) {
                int col = colbase + ct * 16 + l15;
                #pragma unroll
                for (int j = 0; j < 4; ++j) {
                    int r = row0 + rh * 16 + lhi * 4 + j;
                    float bias = (degs[r] > 0) ? biasv[ct] : 0.f;
                    out[(size_t)r * FEAT + col] = acc[rh][ct][j] + bias;
                }
            }
        __syncthreads();
    }
}

extern "C" void kernel_launch(void* const* d_in, const int* in_sizes, int n_in,
                              void* d_out, int out_size, void* d_ws, size_t ws_size,
                              hipStream_t stream) {
    const float* x  = (const float*)d_in[0];
    const int*   ei = (const int*)d_in[1];
    const float* Wl = (const float*)d_in[2];
    const float* bl = (const float*)d_in[3];
    const float* Wr = (const float*)d_in[4];
    float* out = (float*)d_out;

    unsigned short* xbf    = (unsigned short*)d_ws;                  // 25.6 MB
    unsigned short* xbarbf = xbf + (size_t)N_NODES * FEAT;           // 25.6 MB
    int* degs  = (int*)(xbarbf + (size_t)N_NODES * FEAT);            // 400 KB
    int* histm = degs + N_NODES;                                     // 256 KB
    int* ebin  = histm + NBINS * PBLK;                               // 6.4 MB

    prep_kernel<<<(N_NODES * FEAT / 8 + 255) / 256, 256, 0, stream>>>(x, xbf);
    partA_kernel<<<PBLK, 256, 0, stream>>>(ei, histm);
    scan_kernel<<<1, 1024, 0, stream>>>(histm);
    partB_kernel<<<PBLK, 256, 0, stream>>>(ei, histm, ebin);
    agg_kernel<<<NBINS, 256, 0, stream>>>(xbf, histm, ebin, xbarbf, degs);
    gemm_kernel<<<1024, 256, 0, stream>>>(xbf, xbarbf, Wl, bl, Wr, degs, out);
}